// Round 9
// baseline (186.060 us; speedup 1.0000x reference)
//
#include <hip/hip_runtime.h>

// Problem constants (reference shapes)
#define BQ 16
#define NP 4096
#define MP 4096

constexpr int TPB = 256;                         // 4 waves
constexpr int WAVES = 4;
constexpr int FR = 2;                            // B-frags (32 cols) per wave
constexpr int COLS_PER_BLOCK = 32 * FR * WAVES;  // 256
constexpr int ROWSPLIT = 4;                      // 2048 blocks = 8/CU
constexpr int GROUPS_PER_BLOCK = (MP / 32) / ROWSPLIT;  // 32 row-groups

typedef __bf16 bf16x8 __attribute__((ext_vector_type(8)));
typedef float f32x16 __attribute__((ext_vector_type(16)));

union Frag {
    unsigned short u[8];
    bf16x8 v;
    int4 i4;
};

// RNE float -> bf16 bits (no NaN inputs here)
__device__ inline unsigned short f2bf(float f) {
    unsigned u = __float_as_uint(f);
    return (unsigned short)((u + 0x7FFFu + ((u >> 16) & 1u)) >> 16);
}
__device__ inline float bf2f(unsigned short h) {
    return __uint_as_float(((unsigned)h) << 16);
}

__device__ inline float mintree16(const f32x16& d) {
    float m0 = fminf(fminf(d[0], d[1]), d[2]);
    float m1 = fminf(fminf(d[3], d[4]), d[5]);
    float m2 = fminf(fminf(d[6], d[7]), d[8]);
    float m3 = fminf(fminf(d[9], d[10]), d[11]);
    float m4 = fminf(fminf(d[12], d[13]), d[14]);
    return fminf(fminf(fminf(m0, m1), m2), fminf(fminf(m3, m4), d[15]));
}

// ---------------------------------------------------------------------------
// Prep: expand every A-side row point into its two 16B bf16 K-planes, stored
// 32x32-fragment-ready: gy*128KB + group(32 rows)*1KB + row*32B + half*16B.
// Also init minbuf=+inf and out=0 (harness poisons both).
// ---------------------------------------------------------------------------
__global__ __launch_bounds__(TPB) void chamfer_prep_kernel(
    const float* __restrict__ srcp, const float* __restrict__ tgtp,
    unsigned short* __restrict__ table, unsigned int* __restrict__ minbuf,
    float* __restrict__ out) {
    const int idx = blockIdx.x * TPB + threadIdx.x;  // 0..131071
    const int gy  = idx >> 12;                       // dir*16 + b
    const int t   = idx & 4095;                      // row index
    const int dir = gy >> 4, b = gy & 15;
    const float* rows = dir ? (srcp + (size_t)b * NP * 3)
                            : (tgtp + (size_t)b * MP * 3);
    const float* p = rows + (size_t)t * 3;
    float x = p[0], y = p[1], z = p[2];
    unsigned short xh = f2bf(x), yh = f2bf(y), zh = f2bf(z);
    unsigned short xl = f2bf(x - bf2f(xh));
    unsigned short yl = f2bf(y - bf2f(yh));
    unsigned short zl = f2bf(z - bf2f(zh));
    float t2 = fmaf(x, x, fmaf(y, y, z * z));
    unsigned short t2h = f2bf(t2), t2l = f2bf(t2 - bf2f(t2h));
    const unsigned short ONE = 0x3F80;
    Frag p0, p1;
    p0.u[0] = xh; p0.u[1] = yh; p0.u[2] = zh;   // k0..2: hi  (x -2s hi)
    p0.u[3] = xh; p0.u[4] = yh; p0.u[5] = zh;   // k3..5: hi  (x -2s lo)
    p0.u[6] = xl; p0.u[7] = yl;                 // k6..7: lo x,y (x -2s hi)
    p1.u[0] = zl;                               // k8:    lo z
    p1.u[1] = t2h; p1.u[2] = t2l;               // k9..10: t2 (x 1)
    p1.u[3] = ONE; p1.u[4] = ONE;               // k11..12: 1 (x s2 hi/lo)
    p1.u[5] = 0; p1.u[6] = 0; p1.u[7] = 0;
    // shorts offset: gy*65536 + group*512 + row*16 (+8 for half1)
    unsigned short* dst = table + ((size_t)gy << 16) + ((t >> 5) << 9) + ((t & 31) << 4);
    *(int4*)(dst)     = p0.i4;
    *(int4*)(dst + 8) = p1.i4;
    minbuf[idx] = 0x7F800000u;  // +inf
    if (idx == 0) out[0] = 0.0f;
}

// ---------------------------------------------------------------------------
// Main kernel: 32x32x16 MFMA (6.9us/SIMD pipe floor vs 16.6 for 16x16),
// ZERO LDS, ZERO barriers. grid = (16, ROWSPLIT, 2*BQ) = 2048 blocks (8/CU,
// up to 8 waves/SIMD) -- R3..R8 all sat at 2-4 waves/SIMD with the min-tree
// immediately dependent on the just-issued MFMA; ~30us of each kernel was
// exposed MFMA-result/load latency. Fixes here: occupancy 2x, plus a
// software ping-pong so the min-tree of group g-1 overlaps the MFMAs of
// group g (VALU never reads a result younger than one iteration).
// Per-col partial mins merge across ROWSPLIT blocks via uint atomicMin
// (d2>=0 -> float bits order-preserving; verified R1/R4).
// ---------------------------------------------------------------------------
__global__ __launch_bounds__(TPB) void chamfer_main_kernel(
    const float* __restrict__ srcp, const float* __restrict__ tgtp,
    const unsigned short* __restrict__ table,
    unsigned int* __restrict__ minbuf) {
    const int gy  = blockIdx.z;
    const int dir = gy >> 4;
    const int b   = gy & 15;
    // cols(B): dir0 = src points, dir1 = tgt points.
    const float* S = dir ? (tgtp + (size_t)b * MP * 3) : (srcp + (size_t)b * NP * 3);
    unsigned int* mb = minbuf + ((size_t)gy << 12);

    const int tid  = threadIdx.x;
    const int lane = tid & 63;
    const int half = lane >> 5;
    const int col  = lane & 31;
    const int wave = tid >> 6;

    const unsigned short ONE = 0x3F80;

    // ---- FR fixed B-fragments (column side) ----
    Frag bfr[FR];
#pragma unroll
    for (int f = 0; f < FR; ++f) {
        const int sidx = blockIdx.x * COLS_PER_BLOCK + (wave * FR + f) * 32 + col;
        const float* sp = S + (size_t)sidx * 3;
        float x = sp[0], y = sp[1], z = sp[2];
        unsigned short uh0 = f2bf(-2.0f * x), uh1 = f2bf(-2.0f * y), uh2 = f2bf(-2.0f * z);
        unsigned short ul0 = f2bf(-2.0f * x - bf2f(uh0));
        unsigned short ul1 = f2bf(-2.0f * y - bf2f(uh1));
        unsigned short ul2 = f2bf(-2.0f * z - bf2f(uh2));
        float s2 = fmaf(x, x, fmaf(y, y, z * z));
        unsigned short s2h = f2bf(s2), s2l = f2bf(s2 - bf2f(s2h));
        if (half == 0) {  // k = 0..7
            bfr[f].u[0] = uh0; bfr[f].u[1] = uh1; bfr[f].u[2] = uh2;
            bfr[f].u[3] = ul0; bfr[f].u[4] = ul1; bfr[f].u[5] = ul2;
            bfr[f].u[6] = uh0; bfr[f].u[7] = uh1;
        } else {          // k = 8..15
            bfr[f].u[0] = uh2; bfr[f].u[1] = ONE; bfr[f].u[2] = ONE;
            bfr[f].u[3] = s2h; bfr[f].u[4] = s2l;
            bfr[f].u[5] = 0;   bfr[f].u[6] = 0;  bfr[f].u[7] = 0;
        }
    }

    float accm[FR];
#pragma unroll
    for (int f = 0; f < FR; ++f) accm[f] = __int_as_float(0x7F800000);

    const f32x16 zc = {};

    // A-fragment pointer (shorts): slice + group*512 + col*16 + half*8.
    const unsigned short* lptr = table + ((size_t)gy << 16) +
                                 ((size_t)blockIdx.y * GROUPS_PER_BLOCK << 9) +
                                 (col << 4) + (half << 3);

    // ---- software ping-pong: MFMAs for group g overlap min-tree of g-1 ----
    Frag a;
    a.i4 = *(const int4*)(lptr);
    f32x16 dprev[FR];
#pragma unroll
    for (int f = 0; f < FR; ++f)
        dprev[f] = __builtin_amdgcn_mfma_f32_32x32x16_bf16(a.v, bfr[f].v, zc, 0, 0, 0);

#pragma unroll 2
    for (int g = 1; g < GROUPS_PER_BLOCK; ++g) {
        Frag an;
        an.i4 = *(const int4*)(lptr + ((size_t)g << 9));
        f32x16 dcur[FR];
#pragma unroll
        for (int f = 0; f < FR; ++f)
            dcur[f] = __builtin_amdgcn_mfma_f32_32x32x16_bf16(an.v, bfr[f].v, zc, 0, 0, 0);
#pragma unroll
        for (int f = 0; f < FR; ++f)
            accm[f] = fminf(accm[f], mintree16(dprev[f]));
#pragma unroll
        for (int f = 0; f < FR; ++f) dprev[f] = dcur[f];
    }
#pragma unroll
    for (int f = 0; f < FR; ++f)
        accm[f] = fminf(accm[f], mintree16(dprev[f]));

    // ---- epilogue: fold row-halves, clamp, merge via atomicMin ----
#pragma unroll
    for (int f = 0; f < FR; ++f) {
        float m = fminf(accm[f], __shfl_xor(accm[f], 32, 64));
        m = fmaxf(m, 0.0f);
        if (lane < 32) {
            const int sidx = blockIdx.x * COLS_PER_BLOCK + (wave * FR + f) * 32 + col;
            atomicMin(&mb[sidx], __float_as_uint(m));
        }
    }
}

// ---------------------------------------------------------------------------
// Reduce: one block per (dir,b): sum 4096 mins, weight, accumulate scalar.
// ---------------------------------------------------------------------------
__global__ __launch_bounds__(TPB) void chamfer_reduce_kernel(
    const float* __restrict__ minbuf, const float* __restrict__ weights,
    float* __restrict__ out) {
    const int idx = blockIdx.x;  // dir*16 + b
    const int b = idx & 15;
    const float* m0 = minbuf + ((size_t)idx << 12);

    float s = 0.0f;
    for (int i = threadIdx.x; i < 4096; i += TPB) s += m0[i];
#pragma unroll
    for (int off = 32; off > 0; off >>= 1) s += __shfl_down(s, off, 64);

    __shared__ float red[TPB / 64];
    if ((threadIdx.x & 63) == 0) red[threadIdx.x >> 6] = s;
    __syncthreads();
    if (threadIdx.x == 0) {
        float tot = red[0] + red[1] + red[2] + red[3];
        atomicAdd(out, weights[b] * tot * (1.0f / (4096.0f * (float)BQ)));
    }
}

// ---------------------------------------------------------------------------
// Fallback (R6-proven fused kernel) if ws is ever too small.
// ---------------------------------------------------------------------------
__global__ void chamfer_zero_kernel(float* __restrict__ out) { out[0] = 0.0f; }

__global__ __launch_bounds__(TPB) void chamfer_fb_kernel(
    const float* __restrict__ srcp, const float* __restrict__ tgtp,
    const float* __restrict__ wts, float* __restrict__ out) {
    const int gy = blockIdx.y, dir = gy >> 4, b = gy & 15;
    const float* S = dir ? (tgtp + (size_t)b * MP * 3) : (srcp + (size_t)b * NP * 3);
    const float* T = dir ? (srcp + (size_t)b * NP * 3) : (tgtp + (size_t)b * MP * 3);
    const int tid = threadIdx.x, lane = tid & 63, half = lane >> 5,
              col = lane & 31, wave = tid >> 6;
    __shared__ unsigned short sh[256 * 16];
    __shared__ float partial[WAVES];
    const unsigned short ONE = 0x3F80;
    Frag bfr[2];
#pragma unroll
    for (int f = 0; f < 2; ++f) {
        const int sidx = blockIdx.x * 256 + (wave * 2 + f) * 32 + col;
        const float* sp = S + (size_t)sidx * 3;
        float x = sp[0], y = sp[1], z = sp[2];
        unsigned short uh0 = f2bf(-2.0f * x), uh1 = f2bf(-2.0f * y), uh2 = f2bf(-2.0f * z);
        unsigned short ul0 = f2bf(-2.0f * x - bf2f(uh0));
        unsigned short ul1 = f2bf(-2.0f * y - bf2f(uh1));
        unsigned short ul2 = f2bf(-2.0f * z - bf2f(uh2));
        float s2 = fmaf(x, x, fmaf(y, y, z * z));
        unsigned short s2h = f2bf(s2), s2l = f2bf(s2 - bf2f(s2h));
        if (half == 0) {
            bfr[f].u[0] = uh0; bfr[f].u[1] = uh1; bfr[f].u[2] = uh2;
            bfr[f].u[3] = ul0; bfr[f].u[4] = ul1; bfr[f].u[5] = ul2;
            bfr[f].u[6] = uh0; bfr[f].u[7] = uh1;
        } else {
            bfr[f].u[0] = uh2; bfr[f].u[1] = ONE; bfr[f].u[2] = ONE;
            bfr[f].u[3] = s2h; bfr[f].u[4] = s2l;
            bfr[f].u[5] = 0;   bfr[f].u[6] = 0;  bfr[f].u[7] = 0;
        }
    }
    float accm[2] = {__int_as_float(0x7F800000), __int_as_float(0x7F800000)};
    const f32x16 zc = {};
    const int sub = tid >> 5, row = tid & 31;
    float cx, cy, cz;
    { const float* tp = T + (size_t)tid * 3; cx = tp[0]; cy = tp[1]; cz = tp[2]; }
    for (int c = 0; c < MP / 256; ++c) {
        {
            unsigned short xh = f2bf(cx), yh = f2bf(cy), zh = f2bf(cz);
            unsigned short xl = f2bf(cx - bf2f(xh));
            unsigned short yl = f2bf(cy - bf2f(yh));
            unsigned short zl = f2bf(cz - bf2f(zh));
            float t2 = fmaf(cx, cx, fmaf(cy, cy, cz * cz));
            unsigned short t2h = f2bf(t2), t2l = f2bf(t2 - bf2f(t2h));
            Frag p0, p1;
            p0.u[0] = xh; p0.u[1] = yh; p0.u[2] = zh;
            p0.u[3] = xh; p0.u[4] = yh; p0.u[5] = zh;
            p0.u[6] = xl; p0.u[7] = yl;
            p1.u[0] = zl; p1.u[1] = t2h; p1.u[2] = t2l;
            p1.u[3] = ONE; p1.u[4] = ONE; p1.u[5] = 0; p1.u[6] = 0; p1.u[7] = 0;
            *(int4*)&sh[((sub * 2 + 0) * 32 + row) * 8] = p0.i4;
            *(int4*)&sh[((sub * 2 + 1) * 32 + row) * 8] = p1.i4;
        }
        __syncthreads();
        if (c + 1 < MP / 256) {
            const float* tp = T + (size_t)((c + 1) * 256 + tid) * 3;
            cx = tp[0]; cy = tp[1]; cz = tp[2];
        }
#pragma unroll
        for (int sc = 0; sc < 8; ++sc) {
            Frag a;
            a.i4 = *(const int4*)&sh[((sc * 2 + half) * 32 + col) * 8];
#pragma unroll
            for (int f = 0; f < 2; ++f) {
                f32x16 d = __builtin_amdgcn_mfma_f32_32x32x16_bf16(a.v, bfr[f].v, zc, 0, 0, 0);
                accm[f] = fminf(accm[f], mintree16(d));
            }
        }
        __syncthreads();
    }
    float tot = 0.0f;
#pragma unroll
    for (int f = 0; f < 2; ++f) {
        float m = fminf(accm[f], __shfl_xor(accm[f], 32, 64));
        tot += fmaxf(m, 0.0f);
    }
#pragma unroll
    for (int off = 32; off > 0; off >>= 1) tot += __shfl_xor(tot, off, 64);
    if (lane == 0) partial[wave] = tot * 0.5f;
    __syncthreads();
    if (tid == 0) {
        float v = partial[0] + partial[1] + partial[2] + partial[3];
        atomicAdd(out, v * wts[b] * (1.0f / ((float)NP * (float)BQ)));
    }
}

// ---------------------------------------------------------------------------
extern "C" void kernel_launch(void* const* d_in, const int* in_sizes, int n_in,
                              void* d_out, int out_size, void* d_ws, size_t ws_size,
                              hipStream_t stream) {
    const float* src = (const float*)d_in[0];
    const float* tgt = (const float*)d_in[1];
    const float* wts = (const float*)d_in[2];
    float* out = (float*)d_out;

    const size_t MINBUF_BYTES = (size_t)2 * BQ * 4096 * 4;   // 512 KB
    const size_t TABLE_BYTES  = (size_t)2 * BQ * 4096 * 32;  // 4 MB

    if (ws_size >= MINBUF_BYTES + TABLE_BYTES) {
        unsigned int* minbuf  = (unsigned int*)d_ws;
        unsigned short* table = (unsigned short*)((char*)d_ws + MINBUF_BYTES);

        chamfer_prep_kernel<<<(2 * BQ * 4096) / TPB, TPB, 0, stream>>>(
            src, tgt, table, minbuf, out);

        dim3 grid(NP / COLS_PER_BLOCK, ROWSPLIT, 2 * BQ);  // (16,4,32) = 2048
        chamfer_main_kernel<<<grid, TPB, 0, stream>>>(src, tgt, table, minbuf);

        chamfer_reduce_kernel<<<2 * BQ, TPB, 0, stream>>>(
            (const float*)minbuf, wts, out);
    } else {
        chamfer_zero_kernel<<<1, 1, 0, stream>>>(out);
        dim3 grid(NP / 256, 2 * BQ);
        chamfer_fb_kernel<<<grid, TPB, 0, stream>>>(src, tgt, wts, out);
    }
}

// Round 10
// 92.890 us; speedup vs baseline: 2.0030x; 2.0030x over previous
//
#include <hip/hip_runtime.h>

// Problem constants (reference shapes)
#define BQ 16
#define NP 4096
#define MP 4096

constexpr int TPB = 256;                         // 4 waves
constexpr int WAVES = 4;
constexpr int FR = 2;                            // B-frags (32 cols) per wave
constexpr int COLS_PER_BLOCK = 32 * FR * WAVES;  // 256
constexpr int ROWSPLIT = 4;                      // 2048 blocks = 8/CU assigned
constexpr int GROUPS_PER_BLOCK = (MP / 32) / ROWSPLIT;  // 32 row-groups

typedef __bf16 bf16x8 __attribute__((ext_vector_type(8)));
typedef float f32x16 __attribute__((ext_vector_type(16)));

union Frag {
    unsigned short u[8];
    bf16x8 v;
    int4 i4;
};

// RNE float -> bf16 bits (no NaN inputs here)
__device__ inline unsigned short f2bf(float f) {
    unsigned u = __float_as_uint(f);
    return (unsigned short)((u + 0x7FFFu + ((u >> 16) & 1u)) >> 16);
}
__device__ inline float bf2f(unsigned short h) {
    return __uint_as_float(((unsigned)h) << 16);
}

__device__ inline float mintree16(const f32x16& d) {
    float m0 = fminf(fminf(d[0], d[1]), d[2]);
    float m1 = fminf(fminf(d[3], d[4]), d[5]);
    float m2 = fminf(fminf(d[6], d[7]), d[8]);
    float m3 = fminf(fminf(d[9], d[10]), d[11]);
    float m4 = fminf(fminf(d[12], d[13]), d[14]);
    return fminf(fminf(fminf(m0, m1), m2), fminf(fminf(m3, m4), d[15]));
}

// ---------------------------------------------------------------------------
// Prep: pre-expand BOTH sides so the main kernel does zero f2bf VALU work.
// A-table (rows):  [xh yh zh xh yh zh xl yl | zl t2h t2l 1 1 0 0 0]
// B-table (cols):  [uh0 uh1 uh2 ul0 ul1 ul2 uh0 uh1 | uh2 1 1 s2h s2l 0 0 0]
//   (u = -2*coord; pairing gives the R3 bit-exact-verified K=13 dot)
// Layouts (shorts): A: gy*65536 + group*512 + row*16 + half*8
//                   B: gy*65536 + col*16 + half*8
// Also init minbuf=+inf and out=0 (harness poisons both).
// ---------------------------------------------------------------------------
__global__ __launch_bounds__(TPB) void chamfer_prep_kernel(
    const float* __restrict__ srcp, const float* __restrict__ tgtp,
    unsigned short* __restrict__ atab, unsigned short* __restrict__ btab,
    unsigned int* __restrict__ minbuf, float* __restrict__ out) {
    const int idx = blockIdx.x * TPB + threadIdx.x;  // 0..131071
    const int gy  = idx >> 12;                       // dir*16 + b
    const int t   = idx & 4095;                      // point index
    const int dir = gy >> 4, b = gy & 15;
    const unsigned short ONE = 0x3F80;

    // ---- A-side (rows): dir0 = tgt, dir1 = src ----
    {
        const float* rows = dir ? (srcp + (size_t)b * NP * 3)
                                : (tgtp + (size_t)b * MP * 3);
        const float* p = rows + (size_t)t * 3;
        float x = p[0], y = p[1], z = p[2];
        unsigned short xh = f2bf(x), yh = f2bf(y), zh = f2bf(z);
        unsigned short xl = f2bf(x - bf2f(xh));
        unsigned short yl = f2bf(y - bf2f(yh));
        unsigned short zl = f2bf(z - bf2f(zh));
        float t2 = fmaf(x, x, fmaf(y, y, z * z));
        unsigned short t2h = f2bf(t2), t2l = f2bf(t2 - bf2f(t2h));
        Frag p0, p1;
        p0.u[0] = xh; p0.u[1] = yh; p0.u[2] = zh;
        p0.u[3] = xh; p0.u[4] = yh; p0.u[5] = zh;
        p0.u[6] = xl; p0.u[7] = yl;
        p1.u[0] = zl; p1.u[1] = t2h; p1.u[2] = t2l;
        p1.u[3] = ONE; p1.u[4] = ONE; p1.u[5] = 0; p1.u[6] = 0; p1.u[7] = 0;
        unsigned short* dst =
            atab + ((size_t)gy << 16) + ((t >> 5) << 9) + ((t & 31) << 4);
        *(int4*)(dst)     = p0.i4;
        *(int4*)(dst + 8) = p1.i4;
    }

    // ---- B-side (cols): dir0 = src, dir1 = tgt ----
    {
        const float* cols = dir ? (tgtp + (size_t)b * MP * 3)
                                : (srcp + (size_t)b * NP * 3);
        const float* p = cols + (size_t)t * 3;
        float x = p[0], y = p[1], z = p[2];
        unsigned short uh0 = f2bf(-2.0f * x), uh1 = f2bf(-2.0f * y), uh2 = f2bf(-2.0f * z);
        unsigned short ul0 = f2bf(-2.0f * x - bf2f(uh0));
        unsigned short ul1 = f2bf(-2.0f * y - bf2f(uh1));
        unsigned short ul2 = f2bf(-2.0f * z - bf2f(uh2));
        float s2 = fmaf(x, x, fmaf(y, y, z * z));
        unsigned short s2h = f2bf(s2), s2l = f2bf(s2 - bf2f(s2h));
        Frag q0, q1;
        q0.u[0] = uh0; q0.u[1] = uh1; q0.u[2] = uh2;
        q0.u[3] = ul0; q0.u[4] = ul1; q0.u[5] = ul2;
        q0.u[6] = uh0; q0.u[7] = uh1;
        q1.u[0] = uh2; q1.u[1] = ONE; q1.u[2] = ONE;
        q1.u[3] = s2h; q1.u[4] = s2l; q1.u[5] = 0; q1.u[6] = 0; q1.u[7] = 0;
        unsigned short* dst = btab + ((size_t)gy << 16) + ((size_t)t << 4);
        *(int4*)(dst)     = q0.i4;
        *(int4*)(dst + 8) = q1.i4;
    }

    minbuf[idx] = 0x7F800000u;  // +inf
    if (idx == 0) out[0] = 0.0f;
}

// ---------------------------------------------------------------------------
// Main kernel: 32x32x16 MFMA, ZERO LDS, ZERO barriers, ZERO f2bf.
// grid = (16, ROWSPLIT, 2*BQ) = 2048 blocks (8/CU assigned; VGPR ~70-100 ->
// 5-7 waves/SIMD resident). The R3..R9 wall (36-52us for 6 structures vs
// ~7us pipe arithmetic) is modeled as the serial load->MFMA->hazard->min
// chain per iteration; here both MFMAs and the NEXT A-load are issued
// before either min-tree (>=32cyc between an MFMA and the first VALU read
// of its D, covering the MAI->VALU wait states), with live state bounded
// to 2 D-tiles (R9 lesson: 2 generations x unroll spilled at VGPR=256).
// Per-col partial mins merge across ROWSPLIT blocks via uint atomicMin
// (d2>=0 -> float bits order-preserving; verified R1/R4).
// ---------------------------------------------------------------------------
__global__ __launch_bounds__(TPB) void chamfer_main_kernel(
    const unsigned short* __restrict__ atab,
    const unsigned short* __restrict__ btab,
    unsigned int* __restrict__ minbuf) {
    const int gy = blockIdx.z;
    unsigned int* mb = minbuf + ((size_t)gy << 12);

    const int tid  = threadIdx.x;
    const int lane = tid & 63;
    const int half = lane >> 5;
    const int col  = lane & 31;
    const int wave = tid >> 6;

    // ---- FR fixed B-fragments: 2 loads, no expansion ----
    const int c0 = blockIdx.x * COLS_PER_BLOCK + wave * (FR * 32) + col;
    Frag b0, b1;
    b0.i4 = *(const int4*)(btab + ((size_t)gy << 16) + ((size_t)c0 << 4) + (half << 3));
    b1.i4 = *(const int4*)(btab + ((size_t)gy << 16) + ((size_t)(c0 + 32) << 4) + (half << 3));

    float acc0 = __int_as_float(0x7F800000);
    float acc1 = __int_as_float(0x7F800000);

    const f32x16 zc = {};

    // A-fragment pointer (shorts): slice + group*512 + row(col)*16 + half*8.
    const unsigned short* lptr = atab + ((size_t)gy << 16) +
                                 ((size_t)blockIdx.y * GROUPS_PER_BLOCK << 9) +
                                 (col << 4) + (half << 3);

    Frag a;
    a.i4 = *(const int4*)(lptr);

    for (int g = 0; g < GROUPS_PER_BLOCK; ++g) {
        // Issue both MFMAs back-to-back, then next load, THEN consume D --
        // source order gives the scheduler the hazard slack without extra
        // live generations.
        f32x16 d0 = __builtin_amdgcn_mfma_f32_32x32x16_bf16(a.v, b0.v, zc, 0, 0, 0);
        f32x16 d1 = __builtin_amdgcn_mfma_f32_32x32x16_bf16(a.v, b1.v, zc, 0, 0, 0);
        if (g + 1 < GROUPS_PER_BLOCK)
            a.i4 = *(const int4*)(lptr + ((size_t)(g + 1) << 9));
        acc0 = fminf(acc0, mintree16(d0));
        acc1 = fminf(acc1, mintree16(d1));
    }

    // ---- epilogue: fold row-halves, clamp, merge via atomicMin ----
    {
        float m = fminf(acc0, __shfl_xor(acc0, 32, 64));
        m = fmaxf(m, 0.0f);
        if (lane < 32) atomicMin(&mb[c0], __float_as_uint(m));
    }
    {
        float m = fminf(acc1, __shfl_xor(acc1, 32, 64));
        m = fmaxf(m, 0.0f);
        if (lane < 32) atomicMin(&mb[c0 + 32], __float_as_uint(m));
    }
}

// ---------------------------------------------------------------------------
// Reduce: one block per (dir,b): sum 4096 mins, weight, accumulate scalar.
// ---------------------------------------------------------------------------
__global__ __launch_bounds__(TPB) void chamfer_reduce_kernel(
    const float* __restrict__ minbuf, const float* __restrict__ weights,
    float* __restrict__ out) {
    const int idx = blockIdx.x;  // dir*16 + b
    const int b = idx & 15;
    const float* m0 = minbuf + ((size_t)idx << 12);

    float s = 0.0f;
    for (int i = threadIdx.x; i < 4096; i += TPB) s += m0[i];
#pragma unroll
    for (int off = 32; off > 0; off >>= 1) s += __shfl_down(s, off, 64);

    __shared__ float red[TPB / 64];
    if ((threadIdx.x & 63) == 0) red[threadIdx.x >> 6] = s;
    __syncthreads();
    if (threadIdx.x == 0) {
        float tot = red[0] + red[1] + red[2] + red[3];
        atomicAdd(out, weights[b] * tot * (1.0f / (4096.0f * (float)BQ)));
    }
}

// ---------------------------------------------------------------------------
// Fallback (R6-proven fused kernel) if ws is ever too small.
// ---------------------------------------------------------------------------
__global__ void chamfer_zero_kernel(float* __restrict__ out) { out[0] = 0.0f; }

__global__ __launch_bounds__(TPB) void chamfer_fb_kernel(
    const float* __restrict__ srcp, const float* __restrict__ tgtp,
    const float* __restrict__ wts, float* __restrict__ out) {
    const int gy = blockIdx.y, dir = gy >> 4, b = gy & 15;
    const float* S = dir ? (tgtp + (size_t)b * MP * 3) : (srcp + (size_t)b * NP * 3);
    const float* T = dir ? (srcp + (size_t)b * NP * 3) : (tgtp + (size_t)b * MP * 3);
    const int tid = threadIdx.x, lane = tid & 63, half = lane >> 5,
              col = lane & 31, wave = tid >> 6;
    __shared__ unsigned short sh[256 * 16];
    __shared__ float partial[WAVES];
    const unsigned short ONE = 0x3F80;
    Frag bfr[2];
#pragma unroll
    for (int f = 0; f < 2; ++f) {
        const int sidx = blockIdx.x * 256 + (wave * 2 + f) * 32 + col;
        const float* sp = S + (size_t)sidx * 3;
        float x = sp[0], y = sp[1], z = sp[2];
        unsigned short uh0 = f2bf(-2.0f * x), uh1 = f2bf(-2.0f * y), uh2 = f2bf(-2.0f * z);
        unsigned short ul0 = f2bf(-2.0f * x - bf2f(uh0));
        unsigned short ul1 = f2bf(-2.0f * y - bf2f(uh1));
        unsigned short ul2 = f2bf(-2.0f * z - bf2f(uh2));
        float s2 = fmaf(x, x, fmaf(y, y, z * z));
        unsigned short s2h = f2bf(s2), s2l = f2bf(s2 - bf2f(s2h));
        if (half == 0) {
            bfr[f].u[0] = uh0; bfr[f].u[1] = uh1; bfr[f].u[2] = uh2;
            bfr[f].u[3] = ul0; bfr[f].u[4] = ul1; bfr[f].u[5] = ul2;
            bfr[f].u[6] = uh0; bfr[f].u[7] = uh1;
        } else {
            bfr[f].u[0] = uh2; bfr[f].u[1] = ONE; bfr[f].u[2] = ONE;
            bfr[f].u[3] = s2h; bfr[f].u[4] = s2l;
            bfr[f].u[5] = 0;   bfr[f].u[6] = 0;  bfr[f].u[7] = 0;
        }
    }
    float accm[2] = {__int_as_float(0x7F800000), __int_as_float(0x7F800000)};
    const f32x16 zc = {};
    const int sub = tid >> 5, row = tid & 31;
    float cx, cy, cz;
    { const float* tp = T + (size_t)tid * 3; cx = tp[0]; cy = tp[1]; cz = tp[2]; }
    for (int c = 0; c < MP / 256; ++c) {
        {
            unsigned short xh = f2bf(cx), yh = f2bf(cy), zh = f2bf(cz);
            unsigned short xl = f2bf(cx - bf2f(xh));
            unsigned short yl = f2bf(cy - bf2f(yh));
            unsigned short zl = f2bf(cz - bf2f(zh));
            float t2 = fmaf(cx, cx, fmaf(cy, cy, cz * cz));
            unsigned short t2h = f2bf(t2), t2l = f2bf(t2 - bf2f(t2h));
            Frag p0, p1;
            p0.u[0] = xh; p0.u[1] = yh; p0.u[2] = zh;
            p0.u[3] = xh; p0.u[4] = yh; p0.u[5] = zh;
            p0.u[6] = xl; p0.u[7] = yl;
            p1.u[0] = zl; p1.u[1] = t2h; p1.u[2] = t2l;
            p1.u[3] = ONE; p1.u[4] = ONE; p1.u[5] = 0; p1.u[6] = 0; p1.u[7] = 0;
            *(int4*)&sh[((sub * 2 + 0) * 32 + row) * 8] = p0.i4;
            *(int4*)&sh[((sub * 2 + 1) * 32 + row) * 8] = p1.i4;
        }
        __syncthreads();
        if (c + 1 < MP / 256) {
            const float* tp = T + (size_t)((c + 1) * 256 + tid) * 3;
            cx = tp[0]; cy = tp[1]; cz = tp[2];
        }
#pragma unroll
        for (int sc = 0; sc < 8; ++sc) {
            Frag a;
            a.i4 = *(const int4*)&sh[((sc * 2 + half) * 32 + col) * 8];
#pragma unroll
            for (int f = 0; f < 2; ++f) {
                f32x16 d = __builtin_amdgcn_mfma_f32_32x32x16_bf16(a.v, bfr[f].v, zc, 0, 0, 0);
                accm[f] = fminf(accm[f], mintree16(d));
            }
        }
        __syncthreads();
    }
    float tot = 0.0f;
#pragma unroll
    for (int f = 0; f < 2; ++f) {
        float m = fminf(accm[f], __shfl_xor(accm[f], 32, 64));
        tot += fmaxf(m, 0.0f);
    }
#pragma unroll
    for (int off = 32; off > 0; off >>= 1) tot += __shfl_xor(tot, off, 64);
    if (lane == 0) partial[wave] = tot * 0.5f;
    __syncthreads();
    if (tid == 0) {
        float v = partial[0] + partial[1] + partial[2] + partial[3];
        atomicAdd(out, v * wts[b] * (1.0f / ((float)NP * (float)BQ)));
    }
}

// ---------------------------------------------------------------------------
extern "C" void kernel_launch(void* const* d_in, const int* in_sizes, int n_in,
                              void* d_out, int out_size, void* d_ws, size_t ws_size,
                              hipStream_t stream) {
    const float* src = (const float*)d_in[0];
    const float* tgt = (const float*)d_in[1];
    const float* wts = (const float*)d_in[2];
    float* out = (float*)d_out;

    const size_t MINBUF_BYTES = (size_t)2 * BQ * 4096 * 4;   // 512 KB
    const size_t TABLE_BYTES  = (size_t)2 * BQ * 4096 * 32;  // 4 MB each

    if (ws_size >= MINBUF_BYTES + 2 * TABLE_BYTES) {
        unsigned int* minbuf = (unsigned int*)d_ws;
        unsigned short* atab = (unsigned short*)((char*)d_ws + MINBUF_BYTES);
        unsigned short* btab = (unsigned short*)((char*)d_ws + MINBUF_BYTES + TABLE_BYTES);

        chamfer_prep_kernel<<<(2 * BQ * 4096) / TPB, TPB, 0, stream>>>(
            src, tgt, atab, btab, minbuf, out);

        dim3 grid(NP / COLS_PER_BLOCK, ROWSPLIT, 2 * BQ);  // (16,4,32) = 2048
        chamfer_main_kernel<<<grid, TPB, 0, stream>>>(atab, btab, minbuf);

        chamfer_reduce_kernel<<<2 * BQ, TPB, 0, stream>>>(
            (const float*)minbuf, wts, out);
    } else {
        chamfer_zero_kernel<<<1, 1, 0, stream>>>(out);
        dim3 grid(NP / 256, 2 * BQ);
        chamfer_fb_kernel<<<grid, TPB, 0, stream>>>(src, tgt, wts, out);
    }
}